// Round 1
// baseline (123.114 us; speedup 1.0000x reference)
//
#include <hip/hip_runtime.h>

// DUDCLoss: B=4096, C=1024, K=8, eps=1e-5
// loss = para * loss_multi + (1-para) * loss_single
//
// loss_multi  = mean_B[-(s1*log(s2+eps)).sum_C] + mean_B[-(s2*log(s1+eps)).sum_C]
// loss_single = mean_B mean_K [ xent(p1_j,p2_j) + xent(p2_j,p1_j) ]
//   where p_j = softmax over {negatives ∪ positive j}.
// Exact identity: log(e_c/Z_j + eps) = log(e_c + eps*Z_j) - log(Z_j), with
//   e_c = exp(x_c - rowmax), Z_j = Sneg + e_{pos_j}.

constexpr int B_ = 4096;
constexpr int C_ = 1024;
constexpr int K_ = 8;
constexpr float EPSF = 1e-5f;
constexpr int BDIM = 256;
constexpr int PT = C_ / BDIM;  // 4 columns per thread

__global__ __launch_bounds__(BDIM) void dudc_rows(
    const float* __restrict__ out1, const float* __restrict__ out2,
    const int* __restrict__ target, const int* __restrict__ pos_idx,
    float* __restrict__ ws_multi, float* __restrict__ ws_single)
{
  __shared__ float e1s[C_];
  __shared__ float e2s[C_];
  __shared__ float smax[2][4];
  __shared__ float ssum[3][4];
  __shared__ int   pidxs[K_];
  __shared__ float pe1[K_], pe2[K_];
  __shared__ float tpart[4][16];
  __shared__ float ttot[16];
  __shared__ float cont[K_];

  const int i    = blockIdx.x;
  const int t    = threadIdx.x;
  const int wid  = t >> 6;
  const int lane = t & 63;

  const float* x1p = out1 + (size_t)i * C_;
  const float* x2p = out2 + (size_t)i * C_;
  const int*   tgp = target + (size_t)i * C_;

  if (t < K_) pidxs[t] = pos_idx[i * K_ + t];

  float x1[PT], x2[PT];
  int   ng[PT];
#pragma unroll
  for (int u = 0; u < PT; ++u) {
    int c = t + u * BDIM;
    x1[u] = x1p[c];
    x2[u] = x2p[c];
    ng[u] = (tgp[c] == 0);
  }

  // ---- block row-max for out1, out2 (global max: softmax shift-invariant) ----
  float m1 = x1[0], m2 = x2[0];
#pragma unroll
  for (int u = 1; u < PT; ++u) { m1 = fmaxf(m1, x1[u]); m2 = fmaxf(m2, x2[u]); }
  for (int o = 32; o > 0; o >>= 1) {
    m1 = fmaxf(m1, __shfl_down(m1, o));
    m2 = fmaxf(m2, __shfl_down(m2, o));
  }
  if (lane == 0) { smax[0][wid] = m1; smax[1][wid] = m2; }
  __syncthreads();  // covers smax + pidxs
  m1 = fmaxf(fmaxf(smax[0][0], smax[0][1]), fmaxf(smax[0][2], smax[0][3]));
  m2 = fmaxf(fmaxf(smax[1][0], smax[1][1]), fmaxf(smax[1][2], smax[1][3]));

  // ---- exponentials, Sneg, sigmoid-CE part ----
  float e1[PT], e2[PT];
  float sn1 = 0.f, sn2 = 0.f, lm = 0.f;
#pragma unroll
  for (int u = 0; u < PT; ++u) {
    int c = t + u * BDIM;
    e1[u] = __expf(x1[u] - m1);
    e2[u] = __expf(x2[u] - m2);
    e1s[c] = e1[u];
    e2s[c] = e2[u];
    if (ng[u]) { sn1 += e1[u]; sn2 += e2[u]; }
    float s1 = 1.f / (1.f + __expf(-x1[u]));
    float s2 = 1.f / (1.f + __expf(-x2[u]));
    lm -= s1 * __logf(s2 + EPSF) + s2 * __logf(s1 + EPSF);
  }
  for (int o = 32; o > 0; o >>= 1) {
    sn1 += __shfl_down(sn1, o);
    sn2 += __shfl_down(sn2, o);
    lm  += __shfl_down(lm, o);
  }
  if (lane == 0) { ssum[0][wid] = sn1; ssum[1][wid] = sn2; ssum[2][wid] = lm; }
  __syncthreads();  // covers e1s/e2s + ssum
  const float Sn1 = ssum[0][0] + ssum[0][1] + ssum[0][2] + ssum[0][3];
  const float Sn2 = ssum[1][0] + ssum[1][1] + ssum[1][2] + ssum[1][3];

  if (t < K_) { pe1[t] = e1s[pidxs[t]]; pe2[t] = e2s[pidxs[t]]; }
  __syncthreads();  // covers pe1/pe2

  float ez1[K_], ez2[K_];
#pragma unroll
  for (int j = 0; j < K_; ++j) {
    ez1[j] = EPSF * (Sn1 + pe1[j]);  // eps * Z1_j
    ez2[j] = EPSF * (Sn2 + pe2[j]);  // eps * Z2_j
  }

  // ---- hot loop: T1_j = sum_neg e1_c*log(e2_c + eps*Z2_j), T2_j symmetric ----
  float T1[K_], T2[K_];
#pragma unroll
  for (int j = 0; j < K_; ++j) { T1[j] = 0.f; T2[j] = 0.f; }
#pragma unroll
  for (int u = 0; u < PT; ++u) {
    if (ng[u]) {
#pragma unroll
      for (int j = 0; j < K_; ++j) {
        T1[j] += e1[u] * __logf(e2[u] + ez2[j]);
        T2[j] += e2[u] * __logf(e1[u] + ez1[j]);
      }
    }
  }
#pragma unroll
  for (int j = 0; j < K_; ++j) {
    for (int o = 32; o > 0; o >>= 1) {
      T1[j] += __shfl_down(T1[j], o);
      T2[j] += __shfl_down(T2[j], o);
    }
  }
  if (lane == 0) {
#pragma unroll
    for (int j = 0; j < K_; ++j) { tpart[wid][j] = T1[j]; tpart[wid][8 + j] = T2[j]; }
  }
  __syncthreads();
  if (t < 16) ttot[t] = tpart[0][t] + tpart[1][t] + tpart[2][t] + tpart[3][t];
  __syncthreads();
  if (t < K_) {
    int j = t;
    float Z1 = Sn1 + pe1[j];
    float Z2 = Sn2 + pe2[j];
    float x12 = -(ttot[j]     + pe1[j] * __logf(pe2[j] + ez2[j])) / Z1 + __logf(Z2);
    float x21 = -(ttot[8 + j] + pe2[j] * __logf(pe1[j] + ez1[j])) / Z2 + __logf(Z1);
    cont[j] = x12 + x21;
  }
  __syncthreads();
  if (t == 0) {
    float s = 0.f;
#pragma unroll
    for (int j = 0; j < K_; ++j) s += cont[j];
    ws_single[i] = s * (1.f / K_);
    ws_multi[i]  = ssum[2][0] + ssum[2][1] + ssum[2][2] + ssum[2][3];
  }
}

__global__ __launch_bounds__(256) void dudc_final(
    const float* __restrict__ ws_multi, const float* __restrict__ ws_single,
    const float* __restrict__ para, float* __restrict__ out)
{
  __shared__ float sm[2][4];
  const int t = threadIdx.x;
  const int wid = t >> 6, lane = t & 63;
  float a = 0.f, b = 0.f;
  for (int i = t; i < B_; i += 256) { a += ws_multi[i]; b += ws_single[i]; }
  for (int o = 32; o > 0; o >>= 1) {
    a += __shfl_down(a, o);
    b += __shfl_down(b, o);
  }
  if (lane == 0) { sm[0][wid] = a; sm[1][wid] = b; }
  __syncthreads();
  if (t == 0) {
    float lmulti  = (sm[0][0] + sm[0][1] + sm[0][2] + sm[0][3]) * (1.f / B_);
    float lsingle = (sm[1][0] + sm[1][1] + sm[1][2] + sm[1][3]) * (1.f / B_);
    float p = para[0];
    out[0] = lmulti * p + (1.f - p) * lsingle;
  }
}

extern "C" void kernel_launch(void* const* d_in, const int* in_sizes, int n_in,
                              void* d_out, int out_size, void* d_ws, size_t ws_size,
                              hipStream_t stream) {
  const float* out1    = (const float*)d_in[0];
  const float* out2    = (const float*)d_in[1];
  const float* para    = (const float*)d_in[2];
  const int*   target  = (const int*)d_in[3];
  const int*   pos_idx = (const int*)d_in[4];

  float* wsf       = (float*)d_ws;
  float* ws_multi  = wsf;
  float* ws_single = wsf + B_;

  dudc_rows<<<B_, BDIM, 0, stream>>>(out1, out2, target, pos_idx, ws_multi, ws_single);
  dudc_final<<<1, 256, 0, stream>>>(ws_multi, ws_single, para, (float*)d_out);
}